// Round 14
// baseline (78.097 us; speedup 1.0000x reference)
//
#include <hip/hip_runtime.h>
#include <math.h>

#define LL 5
#define HH 32
#define WW 128
#define CC 256
#define HEADS 8
#define DHH 32
#define HW (HH*WW)        // 4096
#define NTOK (LL*HW)      // 20480
#define LN_EPS 1e-5f

typedef short bf16x8 __attribute__((ext_vector_type(8)));
typedef float f32x4 __attribute__((ext_vector_type(4)));
typedef unsigned short u16x8 __attribute__((ext_vector_type(8)));

__device__ __forceinline__ int clamp01(int t) { return t < 0 ? 0 : (t > 1 ? 1 : t); }

__device__ __forceinline__ unsigned short f2b(float f) {
    union { float f; unsigned u; } v; v.f = f;
    unsigned r = v.u + 0x7FFFu + ((v.u >> 16) & 1u);  // RNE
    return (unsigned short)(r >> 16);
}
__device__ __forceinline__ float b2f(unsigned short u) {
    union { unsigned u; float f; } v; v.u = ((unsigned)u) << 16; return v.f;
}

// Fragment-order offset (elements) for a row-major [R][256] matrix:
// frag[panel=row/16][kk=col/32][lane=(col%32)/8*16 + row%16][e=col%8]
__device__ __forceinline__ size_t frag_off(int row, int col) {
    return ((size_t)((row >> 4) * 8 + (col >> 5)) << 9)
         + (((col & 31) >> 3) << 7) + ((row & 15) << 3) + (col & 7);
}

// ---------------- Fused setup: LN (blocks 0..1279), cvt (1280..1407), fold (1408..1471)
__global__ __launch_bounds__(256) void setup_kernel(
        const float* __restrict__ x, const float* __restrict__ g, const float* __restrict__ b,
        unsigned short* __restrict__ xn,
        const float* __restrict__ qw, const float* __restrict__ aw,
        unsigned short* __restrict__ qwb, unsigned short* __restrict__ awb,
        const float* __restrict__ relA, const float* __restrict__ relM,
        const float* __restrict__ kw, const float* __restrict__ vw,
        const float* __restrict__ kb, const float* __restrict__ vb,
        unsigned short* __restrict__ wattb, unsigned short* __restrict__ wmsgb,
        float* __restrict__ batt, float* __restrict__ bmsg) {
    __shared__ float Bl[32][256];
    int blk = blockIdx.x;
    int wave = threadIdx.x >> 6, lane = threadIdx.x & 63;
    if (blk < 1280) {
        // ---- LayerNorm -> bf16 (fragment-order output); block = one 16-row panel
        float4 gv = *(const float4*)(g + lane * 4);
        float4 bv = *(const float4*)(b + lane * 4);
        #pragma unroll
        for (int rr = 0; rr < 4; ++rr) {
            int row = blk * 16 + wave * 4 + rr;
            const float4 xv = *(const float4*)(x + (size_t)row * CC + lane * 4);
            float s1 = xv.x + xv.y + xv.z + xv.w;
            float s2 = xv.x * xv.x + xv.y * xv.y + xv.z * xv.z + xv.w * xv.w;
            #pragma unroll
            for (int off = 32; off; off >>= 1) {
                s1 += __shfl_xor(s1, off, 64);
                s2 += __shfl_xor(s2, off, 64);
            }
            float mu = s1 * (1.0f / CC);
            float inv = rsqrtf(s2 * (1.0f / CC) - mu * mu + LN_EPS);
            ushort4 o;
            o.x = f2b((xv.x - mu) * inv * gv.x + bv.x);
            o.y = f2b((xv.y - mu) * inv * gv.y + bv.y);
            o.z = f2b((xv.z - mu) * inv * gv.z + bv.z);
            o.w = f2b((xv.w - mu) * inv * gv.w + bv.w);
            *(ushort4*)(xn + frag_off(row, lane << 2)) = o;
        }
    } else if (blk < 1408) {
        // ---- fp32 -> bf16 weight conversion into fragment order
        int task = (blk - 1280) * 4 + wave;   // 0..511
        int mtx = task >> 8, rem = task & 255;
        int t = rem >> 7, panel = (rem >> 3) & 15, kk = rem & 7;
        const float* S = (mtx ? aw : qw) + (size_t)t * 65536
                       + (size_t)(panel * 16 + (lane & 15)) * 256 + kk * 32 + (lane >> 4) * 8;
        float4 f0 = *(const float4*)S;
        float4 f1 = *(const float4*)(S + 4);
        u16x8 o;
        o[0] = f2b(f0.x); o[1] = f2b(f0.y); o[2] = f2b(f0.z); o[3] = f2b(f0.w);
        o[4] = f2b(f1.x); o[5] = f2b(f1.y); o[6] = f2b(f1.z); o[7] = f2b(f1.w);
        unsigned short* D = (mtx ? awb : qwb) + (size_t)t * 65536
                          + (((size_t)(panel * 8 + kk)) << 9) + (lane << 3);
        *(u16x8*)D = o;
    } else {
        // ---- fold relation matrices into K/V weights (fragment-order output)
        int fb = blk - 1408;          // 0..63
        int r = fb & 3, m = (fb >> 2) & 7, which = fb >> 5;
        int tsel = r & 1;
        const float* S  = (which ? relM : relA) + ((size_t)r * 8 + m) * 1024;
        const float* Bg = (which ? vw : kw) + (size_t)tsel * 65536 + (size_t)m * 32 * 256;
        const float* bv = (which ? vb : kb) + tsel * 256 + m * 32;
        unsigned short* Wf = (which ? wmsgb : wattb) + (size_t)r * 65536;
        float* bo = (which ? bmsg : batt) + r * 256 + m * 32;

        for (int i = threadIdx.x; i < 32 * 256; i += 256)
            Bl[i >> 8][i & 255] = Bg[(size_t)(i >> 8) * 256 + (i & 255)];
        __syncthreads();

        int a  = threadIdx.x >> 3;        // output row within 32 (j = m*32+a)
        int c0 = (threadIdx.x & 7) * 4;   // column phase; c = c0 + cc*32 + e
        float srow[32];
        #pragma unroll
        for (int bq = 0; bq < 32; ++bq)
            srow[bq] = which ? S[bq * 32 + a] : S[a * 32 + bq];
        float acc[8][4] = {{0.f}};
        #pragma unroll
        for (int bq = 0; bq < 32; ++bq) {
            float s = srow[bq];
            #pragma unroll
            for (int cc = 0; cc < 8; ++cc) {
                float4 bb = *(const float4*)&Bl[bq][c0 + cc * 32];
                acc[cc][0] += s * bb.x; acc[cc][1] += s * bb.y;
                acc[cc][2] += s * bb.z; acc[cc][3] += s * bb.w;
            }
        }
        int colpanel = m * 2 + (a >> 4);
        int jr = a & 15;
        #pragma unroll
        for (int cc = 0; cc < 8; ++cc) {
            ushort4 w4;
            w4.x = f2b(acc[cc][0]); w4.y = f2b(acc[cc][1]);
            w4.z = f2b(acc[cc][2]); w4.w = f2b(acc[cc][3]);
            *(ushort4*)(Wf + (((size_t)(colpanel * 8 + cc)) << 9)
                           + ((c0 >> 3) << 7) + (jr << 3) + (c0 & 7)) = w4;
        }
        if (threadIdx.x < 32) {
            int p = threadIdx.x;
            float s = 0.f;
            #pragma unroll
            for (int bq = 0; bq < 32; ++bq)
                s += (which ? S[bq * 32 + p] : S[p * 32 + bq]) * bv[bq];
            bo[p] = s;
        }
    }
}

// ---------------- Fused QKV-mod GEMM v4: B register-hoisted, A streamed.
// Grid (160, 5): block = (8-panel chunk within one l, s). 800 blocks.
__global__ __launch_bounds__(256, 2) void gemm_qkv(const short* __restrict__ X,
        const short* __restrict__ qwb, const short* __restrict__ wattb,
        const short* __restrict__ wmsgb,
        const float* __restrict__ qb, const float* __restrict__ batt,
        const float* __restrict__ bmsg,
        const float* __restrict__ prior, unsigned short* __restrict__ OutBase) {
    __shared__ float R[4][16][68];
    int chunk = blockIdx.x;                 // 0..159
    int l = chunk >> 5;                     // 32 chunks per l
    int base_panel = l * 256 + (chunk & 31) * 8;
    int base_row = base_panel << 4;
    int s = blockIdx.y;
    int t = clamp01((int)prior[(size_t)l * HW * 3 + 2]);

    const short* Wp; const float* Bp;
    if (s == 0)      { Wp = qwb   + (size_t)t * 65536;                          Bp = qb   + t * 256; }
    else if (s <= 2) { int i2 = (s - 1) * 2 + t; Wp = wattb + (size_t)i2 * 65536; Bp = batt + i2 * 256; }
    else             { int i2 = (s - 3) * 2 + t; Wp = wmsgb + (size_t)i2 * 65536; Bp = bmsg + i2 * 256; }
    unsigned short* Out = OutBase + (size_t)s * NTOK * 256;

    int wave = threadIdx.x >> 6, lane = threadIdx.x & 63;
    int lr = lane & 15;

    // hoist wave's B columns: 4 col-frags x 8 kk = 32KB, held in 128 VGPRs
    bf16x8 bf[4][8];
    #pragma unroll
    for (int nr = 0; nr < 4; ++nr)
        #pragma unroll
        for (int kk = 0; kk < 8; ++kk)
            bf[nr][kk] = *(const bf16x8*)(Wp + (((size_t)((wave * 4 + nr) * 8 + kk)) << 9) + (lane << 3));

    float bias[4];
    #pragma unroll
    for (int nr = 0; nr < 4; ++nr) bias[nr] = Bp[wave * 64 + nr * 16 + lr];

    int q = lane >> 4;
    int c8 = lane & 7;

    // stream 8 A-panels (16 rows each)
    for (int p = 0; p < 8; ++p) {
        const short* Ap = X + (((size_t)(base_panel + p)) << 12);
        bf16x8 af[8];
        #pragma unroll
        for (int kk = 0; kk < 8; ++kk)
            af[kk] = *(const bf16x8*)(Ap + (kk << 9) + (lane << 3));

        f32x4 acc[4];
        #pragma unroll
        for (int nr = 0; nr < 4; ++nr) acc[nr] = (f32x4){0.f, 0.f, 0.f, 0.f};
        #pragma unroll
        for (int kk = 0; kk < 8; ++kk)
            #pragma unroll
            for (int nr = 0; nr < 4; ++nr)
                acc[nr] = __builtin_amdgcn_mfma_f32_16x16x32_bf16(af[kk], bf[nr][kk], acc[nr], 0, 0, 0);

        // epilogue: wave-local LDS repack -> coalesced u16x8 row-major stores
        #pragma unroll
        for (int nr = 0; nr < 4; ++nr)
            #pragma unroll
            for (int rr = 0; rr < 4; ++rr)
                R[wave][q * 4 + rr][nr * 16 + lr] = acc[nr][rr] + bias[nr];
        #pragma unroll
        for (int ph = 0; ph < 2; ++ph) {
            int r = (lane >> 3) + ph * 8;
            float4 v0 = *(const float4*)&R[wave][r][c8 * 8];
            float4 v1 = *(const float4*)&R[wave][r][c8 * 8 + 4];
            u16x8 w;
            w[0] = f2b(v0.x); w[1] = f2b(v0.y); w[2] = f2b(v0.z); w[3] = f2b(v0.w);
            w[4] = f2b(v1.x); w[5] = f2b(v1.y); w[6] = f2b(v1.z); w[7] = f2b(v1.w);
            *(u16x8*)(Out + (size_t)(base_row + p * 16 + r) * 256 + wave * 64 + c8 * 8) = w;
        }
        __builtin_amdgcn_wave_barrier();  // order panel iterations (WAR on R)
    }
}

// ---------------- Fused attention + output projection (round-13, unchanged).
__global__ __launch_bounds__(256) void attn_proj(
        const unsigned short* __restrict__ QKV, const short* __restrict__ awb,
        const float* __restrict__ ab, const int* __restrict__ mask,
        const float* __restrict__ prior, float* __restrict__ out) {
    __shared__ unsigned short Att[32 * 256];  // 16 KB, frag layout
    const size_t TSTR = (size_t)NTOK * 256;
    int tid = threadIdx.x;
    int blkrow = blockIdx.x * 32;
    int i = blkrow >> 12;
    int t = clamp01((int)prior[(size_t)i * HW * 3 + 2]);

    int tok = tid >> 3, m = tid & 7;
    int row = blkrow + tok;
    int hw = row & (HW - 1);

    // ---- Phase 1: thread-local attention
    {
        const unsigned short* Qp = QKV + (size_t)row * 256 + m * 32;
        const unsigned short* Kb = QKV + (size_t)(1 + t) * TSTR + (size_t)hw * 256 + m * 32;
        const unsigned short* Vb = QKV + (size_t)(3 + t) * TSTR + (size_t)hw * 256 + m * 32;

        float qf[32];
        #pragma unroll
        for (int c = 0; c < 4; ++c) {
            bf16x8 qv = *(const bf16x8*)(Qp + c * 8);
            #pragma unroll
            for (int e = 0; e < 8; ++e) qf[c * 8 + e] = b2f((unsigned short)qv[e]);
        }

        const float scale = 0.17677669529663687f;  // 1/sqrt(32)
        float s[LL];
        #pragma unroll
        for (int j = 0; j < LL; ++j) {
            const unsigned short* Kp = Kb + (size_t)j * HW * 256;
            float acc = 0.f;
            #pragma unroll
            for (int c = 0; c < 4; ++c) {
                bf16x8 kv = *(const bf16x8*)(Kp + c * 8);
                #pragma unroll
                for (int e = 0; e < 8; ++e)
                    acc = fmaf(qf[c * 8 + e], b2f((unsigned short)kv[e]), acc);
            }
            int mk = mask[hw * LL + j];
            s[j] = mk ? acc * scale : -1e9f;
        }

        float mx = fmaxf(fmaxf(fmaxf(s[0], s[1]), fmaxf(s[2], s[3])), s[4]);
        float e5[LL], sum = 0.f;
        #pragma unroll
        for (int j = 0; j < LL; ++j) { e5[j] = __expf(s[j] - mx); sum += e5[j]; }
        float inv = 1.f / sum;

        float o[32];
        #pragma unroll
        for (int c = 0; c < 32; ++c) o[c] = 0.f;
        #pragma unroll
        for (int j = 0; j < LL; ++j) {
            const unsigned short* Vp = Vb + (size_t)j * HW * 256;
            float ej = e5[j];
            #pragma unroll
            for (int c = 0; c < 4; ++c) {
                bf16x8 vv = *(const bf16x8*)(Vp + c * 8);
                #pragma unroll
                for (int e = 0; e < 8; ++e)
                    o[c * 8 + e] = fmaf(ej, b2f((unsigned short)vv[e]), o[c * 8 + e]);
            }
        }

        // frag-layout LDS write: panel = tok/16, kk-slot = m, lane' = c8*16 + tok%16
        int panel = tok >> 4, tr = tok & 15;
        #pragma unroll
        for (int c8 = 0; c8 < 4; ++c8) {
            u16x8 w;
            #pragma unroll
            for (int e = 0; e < 8; ++e) w[e] = f2b(o[c8 * 8 + e] * inv);
            *(u16x8*)(&Att[((panel * 8 + m) << 9) + c8 * 128 + tr * 8]) = w;
        }
    }
    __syncthreads();

    // ---- Phase 2: projection GEMM (A from LDS, B=awb[t] from L2)
    int wave = tid >> 6, lane = tid & 63, lr = lane & 15;
    const short* Wp = awb + (size_t)t * 65536;
    const float* Bp = ab + (size_t)t * 256;

    f32x4 acc[2][4];
    #pragma unroll
    for (int mr = 0; mr < 2; ++mr)
        #pragma unroll
        for (int nr = 0; nr < 4; ++nr) acc[mr][nr] = (f32x4){0.f, 0.f, 0.f, 0.f};

    #pragma unroll
    for (int kk = 0; kk < 8; ++kk) {
        bf16x8 af[2], bf[4];
        #pragma unroll
        for (int mr = 0; mr < 2; ++mr)
            af[mr] = *(const bf16x8*)((const short*)Att + ((mr * 8 + kk) << 9) + (lane << 3));
        #pragma unroll
        for (int nr = 0; nr < 4; ++nr)
            bf[nr] = *(const bf16x8*)(Wp + (((size_t)((wave * 4 + nr) * 8 + kk)) << 9) + (lane << 3));
        #pragma unroll
        for (int mr = 0; mr < 2; ++mr)
            #pragma unroll
            for (int nr = 0; nr < 4; ++nr)
                acc[mr][nr] = __builtin_amdgcn_mfma_f32_16x16x32_bf16(af[mr], bf[nr], acc[mr][nr], 0, 0, 0);
    }

    #pragma unroll
    for (int nr = 0; nr < 4; ++nr) {
        int col = wave * 64 + nr * 16 + lr;
        float bias = Bp[col];
        #pragma unroll
        for (int mr = 0; mr < 2; ++mr) {
            #pragma unroll
            for (int rr = 0; rr < 4; ++rr) {
                int orow = blkrow + mr * 16 + (lane >> 4) * 4 + rr;
                out[(size_t)orow * 256 + col] = acc[mr][nr][rr] + bias;
            }
        }
    }
}

extern "C" void kernel_launch(void* const* d_in, const int* in_sizes, int n_in,
                              void* d_out, int out_size, void* d_ws, size_t ws_size,
                              hipStream_t stream) {
    (void)in_sizes; (void)n_in; (void)out_size; (void)ws_size;
    const float* x     = (const float*)d_in[0];
    const int*   mask  = (const int*)d_in[1];
    const float* prior = (const float*)d_in[2];
    const float* ln_g  = (const float*)d_in[3];
    const float* ln_b  = (const float*)d_in[4];
    const float* qw    = (const float*)d_in[5];
    const float* qb    = (const float*)d_in[6];
    const float* kw    = (const float*)d_in[7];
    const float* kb    = (const float*)d_in[8];
    const float* vw    = (const float*)d_in[9];
    const float* vb    = (const float*)d_in[10];
    const float* aw    = (const float*)d_in[11];
    const float* ab    = (const float*)d_in[12];
    const float* relA  = (const float*)d_in[13];
    const float* relM  = (const float*)d_in[14];
    float* out = (float*)d_out;

    char* ws = (char*)d_ws;
    const size_t TOKB = (size_t)NTOK * 256 * 2;  // bf16 token buffer bytes
    unsigned short* xnb  = (unsigned short*)(ws);
    unsigned short* Qb   = (unsigned short*)(ws + TOKB);   // Q, Km0, Km1, Vm0, Vm1 contiguous
    char* wsp = ws + 6 * TOKB;
    unsigned short* qwb   = (unsigned short*)(wsp);            wsp += 131072 * 2;
    unsigned short* awb   = (unsigned short*)(wsp);            wsp += 131072 * 2;
    unsigned short* wattb = (unsigned short*)(wsp);            wsp += 4 * 65536 * 2;
    unsigned short* wmsgb = (unsigned short*)(wsp);            wsp += 4 * 65536 * 2;
    float* batt = (float*)(wsp);                               wsp += 4 * 256 * 4;
    float* bmsg = (float*)(wsp);

    setup_kernel<<<1472, 256, 0, stream>>>(x, ln_g, ln_b, xnb, qw, aw, qwb, awb,
                                           relA, relM, kw, vw, kb, vb,
                                           wattb, wmsgb, batt, bmsg);

    gemm_qkv<<<dim3(160, 5), 256, 0, stream>>>((const short*)xnb,
            (const short*)qwb, (const short*)wattb, (const short*)wmsgb,
            qb, batt, bmsg, prior, Qb);

    attn_proj<<<NTOK / 32, 256, 0, stream>>>(Qb, (const short*)awb, ab, mask, prior, out);
}

// Round 15
// 67.836 us; speedup vs baseline: 1.1513x; 1.1513x over previous
//
#include <hip/hip_runtime.h>
#include <math.h>

#define LL 5
#define HH 32
#define WW 128
#define CC 256
#define HEADS 8
#define DHH 32
#define HW (HH*WW)        // 4096
#define NTOK (LL*HW)      // 20480
#define LN_EPS 1e-5f

typedef short bf16x8 __attribute__((ext_vector_type(8)));
typedef float f32x4 __attribute__((ext_vector_type(4)));
typedef unsigned short u16x8 __attribute__((ext_vector_type(8)));

__device__ __forceinline__ int clamp01(int t) { return t < 0 ? 0 : (t > 1 ? 1 : t); }

__device__ __forceinline__ unsigned short f2b(float f) {
    union { float f; unsigned u; } v; v.f = f;
    unsigned r = v.u + 0x7FFFu + ((v.u >> 16) & 1u);  // RNE
    return (unsigned short)(r >> 16);
}
__device__ __forceinline__ float b2f(unsigned short u) {
    union { unsigned u; float f; } v; v.u = ((unsigned)u) << 16; return v.f;
}

// Fragment-order offset (elements) for a row-major [R][256] matrix:
// frag[panel=row/16][kk=col/32][lane=(col%32)/8*16 + row%16][e=col%8]
__device__ __forceinline__ size_t frag_off(int row, int col) {
    return ((size_t)((row >> 4) * 8 + (col >> 5)) << 9)
         + (((col & 31) >> 3) << 7) + ((row & 15) << 3) + (col & 7);
}

// ---------------- Fused setup: LN (blocks 0..1279), cvt (1280..1407), fold (1408..1471)
__global__ __launch_bounds__(256) void setup_kernel(
        const float* __restrict__ x, const float* __restrict__ g, const float* __restrict__ b,
        unsigned short* __restrict__ xn,
        const float* __restrict__ qw, const float* __restrict__ aw,
        unsigned short* __restrict__ qwb, unsigned short* __restrict__ awb,
        const float* __restrict__ relA, const float* __restrict__ relM,
        const float* __restrict__ kw, const float* __restrict__ vw,
        const float* __restrict__ kb, const float* __restrict__ vb,
        unsigned short* __restrict__ wattb, unsigned short* __restrict__ wmsgb,
        float* __restrict__ batt, float* __restrict__ bmsg) {
    __shared__ float Bl[32][256];
    int blk = blockIdx.x;
    int wave = threadIdx.x >> 6, lane = threadIdx.x & 63;
    if (blk < 1280) {
        // ---- LayerNorm -> bf16 (fragment-order output); block = one 16-row panel
        float4 gv = *(const float4*)(g + lane * 4);
        float4 bv = *(const float4*)(b + lane * 4);
        #pragma unroll
        for (int rr = 0; rr < 4; ++rr) {
            int row = blk * 16 + wave * 4 + rr;
            const float4 xv = *(const float4*)(x + (size_t)row * CC + lane * 4);
            float s1 = xv.x + xv.y + xv.z + xv.w;
            float s2 = xv.x * xv.x + xv.y * xv.y + xv.z * xv.z + xv.w * xv.w;
            #pragma unroll
            for (int off = 32; off; off >>= 1) {
                s1 += __shfl_xor(s1, off, 64);
                s2 += __shfl_xor(s2, off, 64);
            }
            float mu = s1 * (1.0f / CC);
            float inv = rsqrtf(s2 * (1.0f / CC) - mu * mu + LN_EPS);
            ushort4 o;
            o.x = f2b((xv.x - mu) * inv * gv.x + bv.x);
            o.y = f2b((xv.y - mu) * inv * gv.y + bv.y);
            o.z = f2b((xv.z - mu) * inv * gv.z + bv.z);
            o.w = f2b((xv.w - mu) * inv * gv.w + bv.w);
            *(ushort4*)(xn + frag_off(row, lane << 2)) = o;
        }
    } else if (blk < 1408) {
        // ---- fp32 -> bf16 weight conversion into fragment order
        int task = (blk - 1280) * 4 + wave;   // 0..511
        int mtx = task >> 8, rem = task & 255;
        int t = rem >> 7, panel = (rem >> 3) & 15, kk = rem & 7;
        const float* S = (mtx ? aw : qw) + (size_t)t * 65536
                       + (size_t)(panel * 16 + (lane & 15)) * 256 + kk * 32 + (lane >> 4) * 8;
        float4 f0 = *(const float4*)S;
        float4 f1 = *(const float4*)(S + 4);
        u16x8 o;
        o[0] = f2b(f0.x); o[1] = f2b(f0.y); o[2] = f2b(f0.z); o[3] = f2b(f0.w);
        o[4] = f2b(f1.x); o[5] = f2b(f1.y); o[6] = f2b(f1.z); o[7] = f2b(f1.w);
        unsigned short* D = (mtx ? awb : qwb) + (size_t)t * 65536
                          + (((size_t)(panel * 8 + kk)) << 9) + (lane << 3);
        *(u16x8*)D = o;
    } else {
        // ---- fold relation matrices into K/V weights (fragment-order output)
        int fb = blk - 1408;          // 0..63
        int r = fb & 3, m = (fb >> 2) & 7, which = fb >> 5;
        int tsel = r & 1;
        const float* S  = (which ? relM : relA) + ((size_t)r * 8 + m) * 1024;
        const float* Bg = (which ? vw : kw) + (size_t)tsel * 65536 + (size_t)m * 32 * 256;
        const float* bv = (which ? vb : kb) + tsel * 256 + m * 32;
        unsigned short* Wf = (which ? wmsgb : wattb) + (size_t)r * 65536;
        float* bo = (which ? bmsg : batt) + r * 256 + m * 32;

        for (int i = threadIdx.x; i < 32 * 256; i += 256)
            Bl[i >> 8][i & 255] = Bg[(size_t)(i >> 8) * 256 + (i & 255)];
        __syncthreads();

        int a  = threadIdx.x >> 3;        // output row within 32 (j = m*32+a)
        int c0 = (threadIdx.x & 7) * 4;   // column phase; c = c0 + cc*32 + e
        float srow[32];
        #pragma unroll
        for (int bq = 0; bq < 32; ++bq)
            srow[bq] = which ? S[bq * 32 + a] : S[a * 32 + bq];
        float acc[8][4] = {{0.f}};
        #pragma unroll
        for (int bq = 0; bq < 32; ++bq) {
            float s = srow[bq];
            #pragma unroll
            for (int cc = 0; cc < 8; ++cc) {
                float4 bb = *(const float4*)&Bl[bq][c0 + cc * 32];
                acc[cc][0] += s * bb.x; acc[cc][1] += s * bb.y;
                acc[cc][2] += s * bb.z; acc[cc][3] += s * bb.w;
            }
        }
        int colpanel = m * 2 + (a >> 4);
        int jr = a & 15;
        #pragma unroll
        for (int cc = 0; cc < 8; ++cc) {
            ushort4 w4;
            w4.x = f2b(acc[cc][0]); w4.y = f2b(acc[cc][1]);
            w4.z = f2b(acc[cc][2]); w4.w = f2b(acc[cc][3]);
            *(ushort4*)(Wf + (((size_t)(colpanel * 8 + cc)) << 9)
                           + ((c0 >> 3) << 7) + (jr << 3) + (c0 & 7)) = w4;
        }
        if (threadIdx.x < 32) {
            int p = threadIdx.x;
            float s = 0.f;
            #pragma unroll
            for (int bq = 0; bq < 32; ++bq)
                s += (which ? S[bq * 32 + p] : S[p * 32 + bq]) * bv[bq];
            bo[p] = s;
        }
    }
}

// ---------------- Fused QKV-mod GEMM v5: grid (640, 10) = 6400 blocks.
// Block = 32 rows x 128 cols (s = y>>1, col-half = y&1). Max TLP.
__global__ __launch_bounds__(256) void gemm_qkv(const short* __restrict__ X,
        const short* __restrict__ qwb, const short* __restrict__ wattb,
        const short* __restrict__ wmsgb,
        const float* __restrict__ qb, const float* __restrict__ batt,
        const float* __restrict__ bmsg,
        const float* __restrict__ prior, unsigned short* __restrict__ OutBase) {
    __shared__ float R[4][16][36];
    int blkrow = blockIdx.x * 32;
    int s = blockIdx.y >> 1, nh = blockIdx.y & 1;
    int l = blkrow >> 12;
    int t = clamp01((int)prior[(size_t)l * HW * 3 + 2]);

    const short* Wp; const float* Bp;
    if (s == 0)      { Wp = qwb   + (size_t)t * 65536;                          Bp = qb   + t * 256; }
    else if (s <= 2) { int i2 = (s - 1) * 2 + t; Wp = wattb + (size_t)i2 * 65536; Bp = batt + i2 * 256; }
    else             { int i2 = (s - 3) * 2 + t; Wp = wmsgb + (size_t)i2 * 65536; Bp = bmsg + i2 * 256; }
    unsigned short* Out = OutBase + (size_t)s * NTOK * 256;

    int wave = threadIdx.x >> 6, lane = threadIdx.x & 63;
    int lr = lane & 15;
    const short* Xf = X + ((size_t)blockIdx.x << 13);  // 2 row-panels * 8 kk * 512
    int cpb = nh * 8 + wave * 2;                        // colpanel base for this wave

    f32x4 acc[2][2];
    #pragma unroll
    for (int mr = 0; mr < 2; ++mr)
        #pragma unroll
        for (int nr = 0; nr < 2; ++nr) acc[mr][nr] = (f32x4){0.f, 0.f, 0.f, 0.f};

    #pragma unroll
    for (int kk = 0; kk < 8; ++kk) {
        bf16x8 af[2], bf[2];
        #pragma unroll
        for (int mr = 0; mr < 2; ++mr)
            af[mr] = *(const bf16x8*)(Xf + (((size_t)(mr * 8 + kk)) << 9) + (lane << 3));
        #pragma unroll
        for (int nr = 0; nr < 2; ++nr)
            bf[nr] = *(const bf16x8*)(Wp + (((size_t)((cpb + nr) * 8 + kk)) << 9) + (lane << 3));
        #pragma unroll
        for (int mr = 0; mr < 2; ++mr)
            #pragma unroll
            for (int nr = 0; nr < 2; ++nr)
                acc[mr][nr] = __builtin_amdgcn_mfma_f32_16x16x32_bf16(af[mr], bf[nr], acc[mr][nr], 0, 0, 0);
    }

    float bias[2];
    #pragma unroll
    for (int nr = 0; nr < 2; ++nr) bias[nr] = Bp[nh * 128 + wave * 32 + nr * 16 + lr];

    int q = lane >> 4;
    // epilogue: wave-local LDS repack -> coalesced u16x8 row-major stores
    #pragma unroll
    for (int mr = 0; mr < 2; ++mr) {
        #pragma unroll
        for (int nr = 0; nr < 2; ++nr)
            #pragma unroll
            for (int rr = 0; rr < 4; ++rr)
                R[wave][q * 4 + rr][nr * 16 + lr] = acc[mr][nr][rr] + bias[nr];
        int r = lane >> 2, c8 = lane & 3;
        float4 v0 = *(const float4*)&R[wave][r][c8 * 8];
        float4 v1 = *(const float4*)&R[wave][r][c8 * 8 + 4];
        u16x8 w;
        w[0] = f2b(v0.x); w[1] = f2b(v0.y); w[2] = f2b(v0.z); w[3] = f2b(v0.w);
        w[4] = f2b(v1.x); w[5] = f2b(v1.y); w[6] = f2b(v1.z); w[7] = f2b(v1.w);
        *(u16x8*)(Out + (size_t)(blkrow + mr * 16 + r) * 256 + nh * 128 + wave * 32 + c8 * 8) = w;
        __builtin_amdgcn_wave_barrier();  // keep mr iterations ordered (WAR on R)
    }
}

// ---------------- Fused attention + output projection v2.
// Block = 16 tokens x 8 heads = 128 threads; grid NTOK/16 = 1280.
__global__ __launch_bounds__(128) void attn_proj(
        const unsigned short* __restrict__ QKV, const short* __restrict__ awb,
        const float* __restrict__ ab, const int* __restrict__ mask,
        const float* __restrict__ prior, float* __restrict__ out) {
    __shared__ unsigned short Att[16 * 256];  // 8 KB, frag layout (1 panel)
    const size_t TSTR = (size_t)NTOK * 256;
    int tid = threadIdx.x;
    int blkrow = blockIdx.x * 16;
    int i = blkrow >> 12;
    int t = clamp01((int)prior[(size_t)i * HW * 3 + 2]);

    int tok = tid >> 3, m = tid & 7;
    int row = blkrow + tok;
    int hw = row & (HW - 1);

    // ---- Phase 1: thread-local attention (one thread per (tok, head))
    {
        const unsigned short* Qp = QKV + (size_t)row * 256 + m * 32;
        const unsigned short* Kb = QKV + (size_t)(1 + t) * TSTR + (size_t)hw * 256 + m * 32;
        const unsigned short* Vb = QKV + (size_t)(3 + t) * TSTR + (size_t)hw * 256 + m * 32;

        float qf[32];
        #pragma unroll
        for (int c = 0; c < 4; ++c) {
            bf16x8 qv = *(const bf16x8*)(Qp + c * 8);
            #pragma unroll
            for (int e = 0; e < 8; ++e) qf[c * 8 + e] = b2f((unsigned short)qv[e]);
        }

        const float scale = 0.17677669529663687f;  // 1/sqrt(32)
        float s[LL];
        #pragma unroll
        for (int j = 0; j < LL; ++j) {
            const unsigned short* Kp = Kb + (size_t)j * HW * 256;
            float acc = 0.f;
            #pragma unroll
            for (int c = 0; c < 4; ++c) {
                bf16x8 kv = *(const bf16x8*)(Kp + c * 8);
                #pragma unroll
                for (int e = 0; e < 8; ++e)
                    acc = fmaf(qf[c * 8 + e], b2f((unsigned short)kv[e]), acc);
            }
            int mk = mask[hw * LL + j];
            s[j] = mk ? acc * scale : -1e9f;
        }

        float mx = fmaxf(fmaxf(fmaxf(s[0], s[1]), fmaxf(s[2], s[3])), s[4]);
        float e5[LL], sum = 0.f;
        #pragma unroll
        for (int j = 0; j < LL; ++j) { e5[j] = __expf(s[j] - mx); sum += e5[j]; }
        float inv = 1.f / sum;

        float o[32];
        #pragma unroll
        for (int c = 0; c < 32; ++c) o[c] = 0.f;
        #pragma unroll
        for (int j = 0; j < LL; ++j) {
            const unsigned short* Vp = Vb + (size_t)j * HW * 256;
            float ej = e5[j];
            #pragma unroll
            for (int c = 0; c < 4; ++c) {
                bf16x8 vv = *(const bf16x8*)(Vp + c * 8);
                #pragma unroll
                for (int e = 0; e < 8; ++e)
                    o[c * 8 + e] = fmaf(ej, b2f((unsigned short)vv[e]), o[c * 8 + e]);
            }
        }

        // frag-layout LDS write: kk-slot = m, lane' = c8*16 + tok
        #pragma unroll
        for (int c8 = 0; c8 < 4; ++c8) {
            u16x8 w;
            #pragma unroll
            for (int e = 0; e < 8; ++e) w[e] = f2b(o[c8 * 8 + e] * inv);
            *(u16x8*)(&Att[(m << 9) + c8 * 128 + tok * 8]) = w;
        }
    }
    __syncthreads();

    // ---- Phase 2: projection GEMM (1 panel x 256 cols; 2 waves x 128 cols)
    int wave = tid >> 6, lane = tid & 63, lr = lane & 15;
    const short* Wp = awb + (size_t)t * 65536;
    const float* Bp = ab + (size_t)t * 256;

    f32x4 acc[8];
    #pragma unroll
    for (int nr = 0; nr < 8; ++nr) acc[nr] = (f32x4){0.f, 0.f, 0.f, 0.f};

    #pragma unroll
    for (int kk = 0; kk < 8; ++kk) {
        bf16x8 af = *(const bf16x8*)((const short*)Att + (kk << 9) + (lane << 3));
        #pragma unroll
        for (int nr = 0; nr < 8; ++nr) {
            bf16x8 bf = *(const bf16x8*)(Wp + (((size_t)((wave * 8 + nr) * 8 + kk)) << 9) + (lane << 3));
            acc[nr] = __builtin_amdgcn_mfma_f32_16x16x32_bf16(af, bf, acc[nr], 0, 0, 0);
        }
    }

    #pragma unroll
    for (int nr = 0; nr < 8; ++nr) {
        int col = wave * 128 + nr * 16 + lr;
        float bias = Bp[col];
        #pragma unroll
        for (int rr = 0; rr < 4; ++rr) {
            int orow = blkrow + (lane >> 4) * 4 + rr;
            out[(size_t)orow * 256 + col] = acc[nr][rr] + bias;
        }
    }
}

extern "C" void kernel_launch(void* const* d_in, const int* in_sizes, int n_in,
                              void* d_out, int out_size, void* d_ws, size_t ws_size,
                              hipStream_t stream) {
    (void)in_sizes; (void)n_in; (void)out_size; (void)ws_size;
    const float* x     = (const float*)d_in[0];
    const int*   mask  = (const int*)d_in[1];
    const float* prior = (const float*)d_in[2];
    const float* ln_g  = (const float*)d_in[3];
    const float* ln_b  = (const float*)d_in[4];
    const float* qw    = (const float*)d_in[5];
    const float* qb    = (const float*)d_in[6];
    const float* kw    = (const float*)d_in[7];
    const float* kb    = (const float*)d_in[8];
    const float* vw    = (const float*)d_in[9];
    const float* vb    = (const float*)d_in[10];
    const float* aw    = (const float*)d_in[11];
    const float* ab    = (const float*)d_in[12];
    const float* relA  = (const float*)d_in[13];
    const float* relM  = (const float*)d_in[14];
    float* out = (float*)d_out;

    char* ws = (char*)d_ws;
    const size_t TOKB = (size_t)NTOK * 256 * 2;  // bf16 token buffer bytes
    unsigned short* xnb  = (unsigned short*)(ws);
    unsigned short* Qb   = (unsigned short*)(ws + TOKB);   // Q, Km0, Km1, Vm0, Vm1 contiguous
    char* wsp = ws + 6 * TOKB;
    unsigned short* qwb   = (unsigned short*)(wsp);            wsp += 131072 * 2;
    unsigned short* awb   = (unsigned short*)(wsp);            wsp += 131072 * 2;
    unsigned short* wattb = (unsigned short*)(wsp);            wsp += 4 * 65536 * 2;
    unsigned short* wmsgb = (unsigned short*)(wsp);            wsp += 4 * 65536 * 2;
    float* batt = (float*)(wsp);                               wsp += 4 * 256 * 4;
    float* bmsg = (float*)(wsp);

    setup_kernel<<<1472, 256, 0, stream>>>(x, ln_g, ln_b, xnb, qw, aw, qwb, awb,
                                           relA, relM, kw, vw, kb, vb,
                                           wattb, wmsgb, batt, bmsg);

    gemm_qkv<<<dim3(640, 10), 256, 0, stream>>>((const short*)xnb,
            (const short*)qwb, (const short*)wattb, (const short*)wmsgb,
            qb, batt, bmsg, prior, Qb);

    attn_proj<<<NTOK / 16, 128, 0, stream>>>(Qb, (const short*)awb, ab, mask, prior, out);
}

// Round 16
// 64.474 us; speedup vs baseline: 1.2113x; 1.0521x over previous
//
#include <hip/hip_runtime.h>
#include <math.h>

#define LL 5
#define HH 32
#define WW 128
#define CC 256
#define HEADS 8
#define DHH 32
#define HW (HH*WW)        // 4096
#define NTOK (LL*HW)      // 20480
#define LN_EPS 1e-5f

typedef short bf16x8 __attribute__((ext_vector_type(8)));
typedef float f32x4 __attribute__((ext_vector_type(4)));
typedef unsigned short u16x8 __attribute__((ext_vector_type(8)));

__device__ __forceinline__ int clamp01(int t) { return t < 0 ? 0 : (t > 1 ? 1 : t); }

__device__ __forceinline__ unsigned short f2b(float f) {
    union { float f; unsigned u; } v; v.f = f;
    unsigned r = v.u + 0x7FFFu + ((v.u >> 16) & 1u);  // RNE
    return (unsigned short)(r >> 16);
}
__device__ __forceinline__ float b2f(unsigned short u) {
    union { unsigned u; float f; } v; v.u = ((unsigned)u) << 16; return v.f;
}

// Fragment-order offset (elements) for a row-major [R][256] matrix:
// frag[panel=row/16][kk=col/32][lane=(col%32)/8*16 + row%16][e=col%8]
__device__ __forceinline__ size_t frag_off(int row, int col) {
    return ((size_t)((row >> 4) * 8 + (col >> 5)) << 9)
         + (((col & 31) >> 3) << 7) + ((row & 15) << 3) + (col & 7);
}

// ---------------- Fused setup: LN (blocks 0..1279), cvt (1280..1407), fold (1408..1471)
__global__ __launch_bounds__(256) void setup_kernel(
        const float* __restrict__ x, const float* __restrict__ g, const float* __restrict__ b,
        unsigned short* __restrict__ xn,
        const float* __restrict__ qw, const float* __restrict__ aw,
        unsigned short* __restrict__ qwb, unsigned short* __restrict__ awb,
        const float* __restrict__ relA, const float* __restrict__ relM,
        const float* __restrict__ kw, const float* __restrict__ vw,
        const float* __restrict__ kb, const float* __restrict__ vb,
        unsigned short* __restrict__ wattb, unsigned short* __restrict__ wmsgb,
        float* __restrict__ batt, float* __restrict__ bmsg) {
    __shared__ float Bl[32][256];
    int blk = blockIdx.x;
    int wave = threadIdx.x >> 6, lane = threadIdx.x & 63;
    if (blk < 1280) {
        // ---- LayerNorm -> bf16 (fragment-order output); block = one 16-row panel
        float4 gv = *(const float4*)(g + lane * 4);
        float4 bv = *(const float4*)(b + lane * 4);
        #pragma unroll
        for (int rr = 0; rr < 4; ++rr) {
            int row = blk * 16 + wave * 4 + rr;
            const float4 xv = *(const float4*)(x + (size_t)row * CC + lane * 4);
            float s1 = xv.x + xv.y + xv.z + xv.w;
            float s2 = xv.x * xv.x + xv.y * xv.y + xv.z * xv.z + xv.w * xv.w;
            #pragma unroll
            for (int off = 32; off; off >>= 1) {
                s1 += __shfl_xor(s1, off, 64);
                s2 += __shfl_xor(s2, off, 64);
            }
            float mu = s1 * (1.0f / CC);
            float inv = rsqrtf(s2 * (1.0f / CC) - mu * mu + LN_EPS);
            ushort4 o;
            o.x = f2b((xv.x - mu) * inv * gv.x + bv.x);
            o.y = f2b((xv.y - mu) * inv * gv.y + bv.y);
            o.z = f2b((xv.z - mu) * inv * gv.z + bv.z);
            o.w = f2b((xv.w - mu) * inv * gv.w + bv.w);
            *(ushort4*)(xn + frag_off(row, lane << 2)) = o;
        }
    } else if (blk < 1408) {
        // ---- fp32 -> bf16 weight conversion into fragment order
        int task = (blk - 1280) * 4 + wave;   // 0..511
        int mtx = task >> 8, rem = task & 255;
        int t = rem >> 7, panel = (rem >> 3) & 15, kk = rem & 7;
        const float* S = (mtx ? aw : qw) + (size_t)t * 65536
                       + (size_t)(panel * 16 + (lane & 15)) * 256 + kk * 32 + (lane >> 4) * 8;
        float4 f0 = *(const float4*)S;
        float4 f1 = *(const float4*)(S + 4);
        u16x8 o;
        o[0] = f2b(f0.x); o[1] = f2b(f0.y); o[2] = f2b(f0.z); o[3] = f2b(f0.w);
        o[4] = f2b(f1.x); o[5] = f2b(f1.y); o[6] = f2b(f1.z); o[7] = f2b(f1.w);
        unsigned short* D = (mtx ? awb : qwb) + (size_t)t * 65536
                          + (((size_t)(panel * 8 + kk)) << 9) + (lane << 3);
        *(u16x8*)D = o;
    } else {
        // ---- fold relation matrices into K/V weights (fragment-order output)
        int fb = blk - 1408;          // 0..63
        int r = fb & 3, m = (fb >> 2) & 7, which = fb >> 5;
        int tsel = r & 1;
        const float* S  = (which ? relM : relA) + ((size_t)r * 8 + m) * 1024;
        const float* Bg = (which ? vw : kw) + (size_t)tsel * 65536 + (size_t)m * 32 * 256;
        const float* bv = (which ? vb : kb) + tsel * 256 + m * 32;
        unsigned short* Wf = (which ? wmsgb : wattb) + (size_t)r * 65536;
        float* bo = (which ? bmsg : batt) + r * 256 + m * 32;

        for (int i = threadIdx.x; i < 32 * 256; i += 256)
            Bl[i >> 8][i & 255] = Bg[(size_t)(i >> 8) * 256 + (i & 255)];
        __syncthreads();

        int a  = threadIdx.x >> 3;        // output row within 32 (j = m*32+a)
        int c0 = (threadIdx.x & 7) * 4;   // column phase; c = c0 + cc*32 + e
        float srow[32];
        #pragma unroll
        for (int bq = 0; bq < 32; ++bq)
            srow[bq] = which ? S[bq * 32 + a] : S[a * 32 + bq];
        float acc[8][4] = {{0.f}};
        #pragma unroll
        for (int bq = 0; bq < 32; ++bq) {
            float s = srow[bq];
            #pragma unroll
            for (int cc = 0; cc < 8; ++cc) {
                float4 bb = *(const float4*)&Bl[bq][c0 + cc * 32];
                acc[cc][0] += s * bb.x; acc[cc][1] += s * bb.y;
                acc[cc][2] += s * bb.z; acc[cc][3] += s * bb.w;
            }
        }
        int colpanel = m * 2 + (a >> 4);
        int jr = a & 15;
        #pragma unroll
        for (int cc = 0; cc < 8; ++cc) {
            ushort4 w4;
            w4.x = f2b(acc[cc][0]); w4.y = f2b(acc[cc][1]);
            w4.z = f2b(acc[cc][2]); w4.w = f2b(acc[cc][3]);
            *(ushort4*)(Wf + (((size_t)(colpanel * 8 + cc)) << 9)
                           + ((c0 >> 3) << 7) + (jr << 3) + (c0 & 7)) = w4;
        }
        if (threadIdx.x < 32) {
            int p = threadIdx.x;
            float s = 0.f;
            #pragma unroll
            for (int bq = 0; bq < 32; ++bq)
                s += (which ? S[bq * 32 + p] : S[p * 32 + bq]) * bv[bq];
            bo[p] = s;
        }
    }
}

// ---------------- Fused QKV-mod GEMM: grid (NTOK/32, 5) = 3200 blocks. 32x256 tile,
// frag-order inputs, LDS-repacked coalesced row-major bf16 stores.
__global__ __launch_bounds__(256) void gemm_qkv(const short* __restrict__ X,
        const short* __restrict__ qwb, const short* __restrict__ wattb,
        const short* __restrict__ wmsgb,
        const float* __restrict__ qb, const float* __restrict__ batt,
        const float* __restrict__ bmsg,
        const float* __restrict__ prior, unsigned short* __restrict__ OutBase) {
    __shared__ float R[4][16][68];
    int blkrow = blockIdx.x * 32;
    int s = blockIdx.y;
    int l = blkrow >> 12;
    int t = clamp01((int)prior[(size_t)l * HW * 3 + 2]);

    const short* Wp; const float* Bp;
    if (s == 0)      { Wp = qwb   + (size_t)t * 65536;                          Bp = qb   + t * 256; }
    else if (s <= 2) { int i2 = (s - 1) * 2 + t; Wp = wattb + (size_t)i2 * 65536; Bp = batt + i2 * 256; }
    else             { int i2 = (s - 3) * 2 + t; Wp = wmsgb + (size_t)i2 * 65536; Bp = bmsg + i2 * 256; }
    unsigned short* Out = OutBase + (size_t)s * NTOK * 256;

    int wave = threadIdx.x >> 6, lane = threadIdx.x & 63;
    int lr = lane & 15;
    const short* Xf = X + ((size_t)blockIdx.x << 13);  // 2 row-panels * 8 kk * 512

    f32x4 acc[2][4];
    #pragma unroll
    for (int mr = 0; mr < 2; ++mr)
        #pragma unroll
        for (int nr = 0; nr < 4; ++nr) acc[mr][nr] = (f32x4){0.f, 0.f, 0.f, 0.f};

    #pragma unroll
    for (int kk = 0; kk < 8; ++kk) {
        bf16x8 af[2], bf[4];
        #pragma unroll
        for (int mr = 0; mr < 2; ++mr)
            af[mr] = *(const bf16x8*)(Xf + (((size_t)(mr * 8 + kk)) << 9) + (lane << 3));
        #pragma unroll
        for (int nr = 0; nr < 4; ++nr)
            bf[nr] = *(const bf16x8*)(Wp + (((size_t)((wave * 4 + nr) * 8 + kk)) << 9) + (lane << 3));
        #pragma unroll
        for (int mr = 0; mr < 2; ++mr)
            #pragma unroll
            for (int nr = 0; nr < 4; ++nr)
                acc[mr][nr] = __builtin_amdgcn_mfma_f32_16x16x32_bf16(af[mr], bf[nr], acc[mr][nr], 0, 0, 0);
    }

    float bias[4];
    #pragma unroll
    for (int nr = 0; nr < 4; ++nr) bias[nr] = Bp[wave * 64 + nr * 16 + lr];

    int q = lane >> 4;
    int c8 = lane & 7;
    // epilogue: wave-local LDS repack -> coalesced u16x8 row-major stores
    #pragma unroll
    for (int mr = 0; mr < 2; ++mr) {
        #pragma unroll
        for (int nr = 0; nr < 4; ++nr)
            #pragma unroll
            for (int rr = 0; rr < 4; ++rr)
                R[wave][q * 4 + rr][nr * 16 + lr] = acc[mr][nr][rr] + bias[nr];
        #pragma unroll
        for (int p = 0; p < 2; ++p) {
            int r = (lane >> 3) + p * 8;
            float4 v0 = *(const float4*)&R[wave][r][c8 * 8];
            float4 v1 = *(const float4*)&R[wave][r][c8 * 8 + 4];
            u16x8 w;
            w[0] = f2b(v0.x); w[1] = f2b(v0.y); w[2] = f2b(v0.z); w[3] = f2b(v0.w);
            w[4] = f2b(v1.x); w[5] = f2b(v1.y); w[6] = f2b(v1.z); w[7] = f2b(v1.w);
            *(u16x8*)(Out + (size_t)(blkrow + mr * 16 + r) * 256 + wave * 64 + c8 * 8) = w;
        }
        __builtin_amdgcn_wave_barrier();  // keep mr iterations ordered (WAR on R)
    }
}

// ---------------- Fused attention + output projection.
// Block = 32 tokens x 8 heads = 256 threads; grid NTOK/32 = 640.
// Phase 1: thread-local attention -> LDS (MFMA A-frag layout).
// Phase 2: 32x256 @ awb[t]^T + ab -> fp32 out (row-major).
__global__ __launch_bounds__(256) void attn_proj(
        const unsigned short* __restrict__ QKV, const short* __restrict__ awb,
        const float* __restrict__ ab, const int* __restrict__ mask,
        const float* __restrict__ prior, float* __restrict__ out) {
    __shared__ unsigned short Att[32 * 256];  // 16 KB, frag layout
    const size_t TSTR = (size_t)NTOK * 256;
    int tid = threadIdx.x;
    int blkrow = blockIdx.x * 32;
    int i = blkrow >> 12;
    int t = clamp01((int)prior[(size_t)i * HW * 3 + 2]);

    int tok = tid >> 3, m = tid & 7;
    int row = blkrow + tok;
    int hw = row & (HW - 1);

    // ---- Phase 1: thread-local attention
    {
        const unsigned short* Qp = QKV + (size_t)row * 256 + m * 32;
        const unsigned short* Kb = QKV + (size_t)(1 + t) * TSTR + (size_t)hw * 256 + m * 32;
        const unsigned short* Vb = QKV + (size_t)(3 + t) * TSTR + (size_t)hw * 256 + m * 32;

        float qf[32];
        #pragma unroll
        for (int c = 0; c < 4; ++c) {
            bf16x8 qv = *(const bf16x8*)(Qp + c * 8);
            #pragma unroll
            for (int e = 0; e < 8; ++e) qf[c * 8 + e] = b2f((unsigned short)qv[e]);
        }

        const float scale = 0.17677669529663687f;  // 1/sqrt(32)
        float s[LL];
        #pragma unroll
        for (int j = 0; j < LL; ++j) {
            const unsigned short* Kp = Kb + (size_t)j * HW * 256;
            float acc = 0.f;
            #pragma unroll
            for (int c = 0; c < 4; ++c) {
                bf16x8 kv = *(const bf16x8*)(Kp + c * 8);
                #pragma unroll
                for (int e = 0; e < 8; ++e)
                    acc = fmaf(qf[c * 8 + e], b2f((unsigned short)kv[e]), acc);
            }
            int mk = mask[hw * LL + j];
            s[j] = mk ? acc * scale : -1e9f;
        }

        float mx = fmaxf(fmaxf(fmaxf(s[0], s[1]), fmaxf(s[2], s[3])), s[4]);
        float e5[LL], sum = 0.f;
        #pragma unroll
        for (int j = 0; j < LL; ++j) { e5[j] = __expf(s[j] - mx); sum += e5[j]; }
        float inv = 1.f / sum;

        float o[32];
        #pragma unroll
        for (int c = 0; c < 32; ++c) o[c] = 0.f;
        #pragma unroll
        for (int j = 0; j < LL; ++j) {
            const unsigned short* Vp = Vb + (size_t)j * HW * 256;
            float ej = e5[j];
            #pragma unroll
            for (int c = 0; c < 4; ++c) {
                bf16x8 vv = *(const bf16x8*)(Vp + c * 8);
                #pragma unroll
                for (int e = 0; e < 8; ++e)
                    o[c * 8 + e] = fmaf(ej, b2f((unsigned short)vv[e]), o[c * 8 + e]);
            }
        }

        // frag-layout LDS write: panel = tok/16, kk-slot = m, lane' = c8*16 + tok%16
        int panel = tok >> 4, tr = tok & 15;
        #pragma unroll
        for (int c8 = 0; c8 < 4; ++c8) {
            u16x8 w;
            #pragma unroll
            for (int e = 0; e < 8; ++e) w[e] = f2b(o[c8 * 8 + e] * inv);
            *(u16x8*)(&Att[((panel * 8 + m) << 9) + c8 * 128 + tr * 8]) = w;
        }
    }
    __syncthreads();

    // ---- Phase 2: projection GEMM (A from LDS, B=awb[t] from L2)
    int wave = tid >> 6, lane = tid & 63, lr = lane & 15;
    const short* Wp = awb + (size_t)t * 65536;
    const float* Bp = ab + (size_t)t * 256;

    f32x4 acc[2][4];
    #pragma unroll
    for (int mr = 0; mr < 2; ++mr)
        #pragma unroll
        for (int nr = 0; nr < 4; ++nr) acc[mr][nr] = (f32x4){0.f, 0.f, 0.f, 0.f};

    #pragma unroll
    for (int kk = 0; kk < 8; ++kk) {
        bf16x8 af[2], bf[4];
        #pragma unroll
        for (int mr = 0; mr < 2; ++mr)
            af[mr] = *(const bf16x8*)((const short*)Att + ((mr * 8 + kk) << 9) + (lane << 3));
        #pragma unroll
        for (int nr = 0; nr < 4; ++nr)
            bf[nr] = *(const bf16x8*)(Wp + (((size_t)((wave * 4 + nr) * 8 + kk)) << 9) + (lane << 3));
        #pragma unroll
        for (int mr = 0; mr < 2; ++mr)
            #pragma unroll
            for (int nr = 0; nr < 4; ++nr)
                acc[mr][nr] = __builtin_amdgcn_mfma_f32_16x16x32_bf16(af[mr], bf[nr], acc[mr][nr], 0, 0, 0);
    }

    #pragma unroll
    for (int nr = 0; nr < 4; ++nr) {
        int col = wave * 64 + nr * 16 + lr;
        float bias = Bp[col];
        #pragma unroll
        for (int mr = 0; mr < 2; ++mr) {
            #pragma unroll
            for (int rr = 0; rr < 4; ++rr) {
                int orow = blkrow + mr * 16 + (lane >> 4) * 4 + rr;
                out[(size_t)orow * 256 + col] = acc[mr][nr][rr] + bias;
            }
        }
    }
}

extern "C" void kernel_launch(void* const* d_in, const int* in_sizes, int n_in,
                              void* d_out, int out_size, void* d_ws, size_t ws_size,
                              hipStream_t stream) {
    (void)in_sizes; (void)n_in; (void)out_size; (void)ws_size;
    const float* x     = (const float*)d_in[0];
    const int*   mask  = (const int*)d_in[1];
    const float* prior = (const float*)d_in[2];
    const float* ln_g  = (const float*)d_in[3];
    const float* ln_b  = (const float*)d_in[4];
    const float* qw    = (const float*)d_in[5];
    const float* qb    = (const float*)d_in[6];
    const float* kw    = (const float*)d_in[7];
    const float* kb    = (const float*)d_in[8];
    const float* vw    = (const float*)d_in[9];
    const float* vb    = (const float*)d_in[10];
    const float* aw    = (const float*)d_in[11];
    const float* ab    = (const float*)d_in[12];
    const float* relA  = (const float*)d_in[13];
    const float* relM  = (const float*)d_in[14];
    float* out = (float*)d_out;

    char* ws = (char*)d_ws;
    const size_t TOKB = (size_t)NTOK * 256 * 2;  // bf16 token buffer bytes
    unsigned short* xnb  = (unsigned short*)(ws);
    unsigned short* Qb   = (unsigned short*)(ws + TOKB);   // Q, Km0, Km1, Vm0, Vm1 contiguous
    char* wsp = ws + 6 * TOKB;
    unsigned short* qwb   = (unsigned short*)(wsp);            wsp += 131072 * 2;
    unsigned short* awb   = (unsigned short*)(wsp);            wsp += 131072 * 2;
    unsigned short* wattb = (unsigned short*)(wsp);            wsp += 4 * 65536 * 2;
    unsigned short* wmsgb = (unsigned short*)(wsp);            wsp += 4 * 65536 * 2;
    float* batt = (float*)(wsp);                               wsp += 4 * 256 * 4;
    float* bmsg = (float*)(wsp);

    setup_kernel<<<1472, 256, 0, stream>>>(x, ln_g, ln_b, xnb, qw, aw, qwb, awb,
                                           relA, relM, kw, vw, kb, vb,
                                           wattb, wmsgb, batt, bmsg);

    gemm_qkv<<<dim3(NTOK / 32, 5), 256, 0, stream>>>((const short*)xnb,
            (const short*)qwb, (const short*)wattb, (const short*)wmsgb,
            qb, batt, bmsg, prior, Qb);

    attn_proj<<<NTOK / 32, 256, 0, stream>>>(Qb, (const short*)awb, ab, mask, prior, out);
}